// Round 1
// baseline (2073.330 us; speedup 1.0000x reference)
//
#include <hip/hip_runtime.h>

// PrototypeNetwork: per-class prototypes from cosine-similarity row-means.
// Math (see reference): u = f/max(||f||,eps); m[c] = seg_sum(u); n_c = counts;
// w_i = (u_i . m[lab_i] - u_i.u_i) / (max(n_c-1,1)*max(n_c,1));
// proto[c] = seg_sum(w_i * f_i) / max(n_c,1).
//
// Two passes over the 512MB feature matrix (m must be final before pass 2).
// Wave-per-sample; lane l owns dims {l, l+64} -> LDS atomics land 2 lanes/bank
// (free per m136). Per-block LDS accumulators (51.6KB -> 3 blocks/CU), one
// global-atomic flush per block.

namespace {

constexpr int C = 100;
constexpr int D = 128;
constexpr float EPS = 1e-8f;
constexpr int BLOCK = 256;
constexpr int GRID = 768;  // 3 blocks/CU * 256 CU (LDS-limited occupancy)

__global__ __launch_bounds__(BLOCK) void k_stats(const float* __restrict__ feat,
                                                 const int* __restrict__ lab,
                                                 float* __restrict__ m_g,
                                                 float* __restrict__ cnt_g,
                                                 int n) {
  __shared__ float m_loc[C * D];
  __shared__ float cnt_loc[C];
  for (int i = threadIdx.x; i < C * D; i += BLOCK) m_loc[i] = 0.f;
  if (threadIdx.x < C) cnt_loc[threadIdx.x] = 0.f;
  __syncthreads();

  const int lane = threadIdx.x & 63;
  const int wid = (blockIdx.x * BLOCK + threadIdx.x) >> 6;
  const int nw = (GRID * BLOCK) >> 6;

  for (int i = wid; i < n; i += nw) {
    const float* row = feat + (size_t)i * D;
    float x0 = row[lane];
    float x1 = row[lane + 64];
    float ss = x0 * x0 + x1 * x1;
#pragma unroll
    for (int off = 32; off > 0; off >>= 1) ss += __shfl_xor(ss, off, 64);
    float inv = 1.0f / fmaxf(sqrtf(ss), EPS);
    int c = lab[i];
    atomicAdd(&m_loc[c * D + lane], x0 * inv);
    atomicAdd(&m_loc[c * D + lane + 64], x1 * inv);
    if (lane == 0) atomicAdd(&cnt_loc[c], 1.0f);
  }
  __syncthreads();

  for (int i = threadIdx.x; i < C * D; i += BLOCK) atomicAdd(&m_g[i], m_loc[i]);
  if (threadIdx.x < C) atomicAdd(&cnt_g[threadIdx.x], cnt_loc[threadIdx.x]);
}

__global__ __launch_bounds__(BLOCK) void k_proto(const float* __restrict__ feat,
                                                 const int* __restrict__ lab,
                                                 const float* __restrict__ m_g,
                                                 const float* __restrict__ cnt_g,
                                                 float* __restrict__ proto_g,
                                                 int n) {
  __shared__ float p_loc[C * D];
  __shared__ float cnt_loc[C];
  for (int i = threadIdx.x; i < C * D; i += BLOCK) p_loc[i] = 0.f;
  if (threadIdx.x < C) cnt_loc[threadIdx.x] = cnt_g[threadIdx.x];
  __syncthreads();

  const int lane = threadIdx.x & 63;
  const int wid = (blockIdx.x * BLOCK + threadIdx.x) >> 6;
  const int nw = (GRID * BLOCK) >> 6;

  for (int i = wid; i < n; i += nw) {
    const float* row = feat + (size_t)i * D;
    int c = lab[i];
    float x0 = row[lane];
    float x1 = row[lane + 64];
    // m is 50KB, L2/L1-resident and shared by all waves -> read from global
    // (keeps LDS at 51.6KB so we keep 3 blocks/CU).
    float m0 = m_g[c * D + lane];
    float m1 = m_g[c * D + lane + 64];
    float ss = x0 * x0 + x1 * x1;
    float pm = x0 * m0 + x1 * m1;
#pragma unroll
    for (int off = 32; off > 0; off >>= 1) {
      ss += __shfl_xor(ss, off, 64);
      pm += __shfl_xor(pm, off, 64);
    }
    float inv = 1.0f / fmaxf(sqrtf(ss), EPS);
    // row_sum = u.m - u.u  (u.u computed exactly as ss*inv^2: handles f==0)
    float row_sum = pm * inv - ss * inv * inv;
    float nc = cnt_loc[c];
    float w = row_sum / (fmaxf(nc - 1.f, 1.f) * fmaxf(nc, 1.f));
    atomicAdd(&p_loc[c * D + lane], w * x0);
    atomicAdd(&p_loc[c * D + lane + 64], w * x1);
  }
  __syncthreads();

  for (int i = threadIdx.x; i < C * D; i += BLOCK) atomicAdd(&proto_g[i], p_loc[i]);
}

__global__ void k_final(const float* __restrict__ proto_g,
                        const float* __restrict__ cnt_g,
                        float* __restrict__ out) {
  int i = blockIdx.x * BLOCK + threadIdx.x;
  if (i < C * D) out[i] = proto_g[i] / fmaxf(cnt_g[i / D], 1.f);
}

}  // namespace

extern "C" void kernel_launch(void* const* d_in, const int* in_sizes, int n_in,
                              void* d_out, int out_size, void* d_ws, size_t ws_size,
                              hipStream_t stream) {
  const float* feat = (const float*)d_in[0];
  const int* lab = (const int*)d_in[1];  // harness delivers integer inputs as int32
  const int n = in_sizes[0] / D;

  // ws layout: m[C*D] | cnt[C] | proto[C*D]   (all fp32, zero-initialized)
  float* m_g = (float*)d_ws;
  float* cnt_g = m_g + C * D;
  float* proto_g = cnt_g + C;
  hipMemsetAsync(d_ws, 0, (size_t)(2 * C * D + C) * sizeof(float), stream);

  k_stats<<<GRID, BLOCK, 0, stream>>>(feat, lab, m_g, cnt_g, n);
  k_proto<<<GRID, BLOCK, 0, stream>>>(feat, lab, m_g, cnt_g, proto_g, n);
  k_final<<<(C * D + BLOCK - 1) / BLOCK, BLOCK, 0, stream>>>(proto_g, cnt_g, (float*)d_out);
}

// Round 2
// 1914.343 us; speedup vs baseline: 1.0831x; 1.0831x over previous
//
#include <hip/hip_runtime.h>

// PrototypeNetwork: per-class prototypes from cosine-similarity row-means.
//   u = f/max(||f||,eps); m[c] = seg_sum(u); n_c = counts;
//   w_i = (u_i.m[lab_i] - u_i.u_i) / (max(n_c-1,1)*max(n_c,1));
//   proto[c] = seg_sum(w_i * f_i) / max(n_c,1).
//
// R1 was latency-bound (4.7% HBM, VALU 15%): 512 B/wave/iter with a ~3-6K cyc
// dependent chain (lab->m->dot->6 shuffles->atomic). R2: 8 samples/wave/iter
// (half-wave per sample, float4 loads -> 4 KB/iter), 5-deep 32-lane shuffle
// reductions with 4-8 interleaved independent chains, and a permuted LDS
// accumulator layout [class][4][32] so float4-component atomics land 2
// lanes/bank (free per m136).

namespace {

constexpr int C = 100;
constexpr int D = 128;
constexpr float EPS = 1e-8f;
constexpr int BLOCK = 256;
constexpr int GRID = 768;   // ~3 blocks/CU (LDS-limited) * 256 CU
constexpr int S = 8;        // samples per wave per iteration (2 per sub-step)

__global__ __launch_bounds__(BLOCK) void k_stats(const float4* __restrict__ feat4,
                                                 const int* __restrict__ lab,
                                                 float* __restrict__ m_g,
                                                 float* __restrict__ cnt_g,
                                                 int n) {
  // Permuted layout: LDS index class*128 + q*32 + sl  <->  dim d = 4*sl + q.
  __shared__ float m_loc[C * D];
  __shared__ float cnt_loc[C];
  for (int i = threadIdx.x; i < C * D; i += BLOCK) m_loc[i] = 0.f;
  if (threadIdx.x < C) cnt_loc[threadIdx.x] = 0.f;
  __syncthreads();

  const int lane = threadIdx.x & 63;
  const int half = lane >> 5;   // which of 2 samples per sub-step
  const int sl = lane & 31;     // lane within half: owns dims 4*sl..4*sl+3
  const int wid = (blockIdx.x * BLOCK + threadIdx.x) >> 6;
  const int nw = (GRID * BLOCK) >> 6;

  for (int base = wid * S; base < n; base += nw * S) {
    float4 x[4];
    int c[4];
    bool valid[4];
#pragma unroll
    for (int s = 0; s < 4; ++s) {
      int idx = base + 2 * s + half;
      valid[s] = idx < n;
      int ci = valid[s] ? idx : n - 1;  // clamped load, accumulate skipped
      x[s] = feat4[(size_t)ci * 32 + sl];
      c[s] = lab[ci];
    }
    float ss[4];
#pragma unroll
    for (int s = 0; s < 4; ++s)
      ss[s] = x[s].x * x[s].x + x[s].y * x[s].y + x[s].z * x[s].z + x[s].w * x[s].w;
#pragma unroll
    for (int off = 16; off > 0; off >>= 1) {
#pragma unroll
      for (int s = 0; s < 4; ++s) ss[s] += __shfl_xor(ss[s], off, 64);
    }
#pragma unroll
    for (int s = 0; s < 4; ++s) {
      if (!valid[s]) continue;
      float inv = 1.0f / fmaxf(sqrtf(ss[s]), EPS);
      float* mp = &m_loc[c[s] * D];
      atomicAdd(&mp[0 * 32 + sl], x[s].x * inv);
      atomicAdd(&mp[1 * 32 + sl], x[s].y * inv);
      atomicAdd(&mp[2 * 32 + sl], x[s].z * inv);
      atomicAdd(&mp[3 * 32 + sl], x[s].w * inv);
      if (sl == 0) atomicAdd(&cnt_loc[c[s]], 1.0f);
    }
  }
  __syncthreads();

  // Flush permuted -> natural layout (m_g is dim-major so pass 2 float4-loads it).
  for (int i = threadIdx.x; i < C * D; i += BLOCK) {
    int cls = i >> 7, a = i & 127, q = a >> 5, s2 = a & 31;
    atomicAdd(&m_g[cls * D + s2 * 4 + q], m_loc[i]);
  }
  if (threadIdx.x < C) atomicAdd(&cnt_g[threadIdx.x], cnt_loc[threadIdx.x]);
}

__global__ __launch_bounds__(BLOCK) void k_proto(const float4* __restrict__ feat4,
                                                 const int* __restrict__ lab,
                                                 const float4* __restrict__ m_g4,
                                                 const float* __restrict__ cnt_g,
                                                 float* __restrict__ proto_g,
                                                 int n) {
  __shared__ float p_loc[C * D];  // permuted layout, same as k_stats
  __shared__ float cnt_loc[C];
  for (int i = threadIdx.x; i < C * D; i += BLOCK) p_loc[i] = 0.f;
  if (threadIdx.x < C) cnt_loc[threadIdx.x] = cnt_g[threadIdx.x];
  __syncthreads();

  const int lane = threadIdx.x & 63;
  const int half = lane >> 5;
  const int sl = lane & 31;
  const int wid = (blockIdx.x * BLOCK + threadIdx.x) >> 6;
  const int nw = (GRID * BLOCK) >> 6;

  for (int base = wid * S; base < n; base += nw * S) {
    float4 x[4], mv[4];
    int c[4];
    bool valid[4];
#pragma unroll
    for (int s = 0; s < 4; ++s) {
      int idx = base + 2 * s + half;
      valid[s] = idx < n;
      int ci = valid[s] ? idx : n - 1;
      x[s] = feat4[(size_t)ci * 32 + sl];
      c[s] = lab[ci];
    }
#pragma unroll
    for (int s = 0; s < 4; ++s) mv[s] = m_g4[c[s] * 32 + sl];  // 50 KB, L1/L2-hot

    float ss[4], pm[4];
#pragma unroll
    for (int s = 0; s < 4; ++s) {
      ss[s] = x[s].x * x[s].x + x[s].y * x[s].y + x[s].z * x[s].z + x[s].w * x[s].w;
      pm[s] = x[s].x * mv[s].x + x[s].y * mv[s].y + x[s].z * mv[s].z + x[s].w * mv[s].w;
    }
#pragma unroll
    for (int off = 16; off > 0; off >>= 1) {
#pragma unroll
      for (int s = 0; s < 4; ++s) {
        ss[s] += __shfl_xor(ss[s], off, 64);
        pm[s] += __shfl_xor(pm[s], off, 64);
      }
    }
#pragma unroll
    for (int s = 0; s < 4; ++s) {
      if (!valid[s]) continue;
      float inv = 1.0f / fmaxf(sqrtf(ss[s]), EPS);
      float row_sum = pm[s] * inv - ss[s] * inv * inv;  // u.m - u.u (f==0 safe)
      float nc = cnt_loc[c[s]];
      float w = row_sum / (fmaxf(nc - 1.f, 1.f) * fmaxf(nc, 1.f));
      float* pp = &p_loc[c[s] * D];
      atomicAdd(&pp[0 * 32 + sl], w * x[s].x);
      atomicAdd(&pp[1 * 32 + sl], w * x[s].y);
      atomicAdd(&pp[2 * 32 + sl], w * x[s].z);
      atomicAdd(&pp[3 * 32 + sl], w * x[s].w);
    }
  }
  __syncthreads();

  for (int i = threadIdx.x; i < C * D; i += BLOCK) {
    int cls = i >> 7, a = i & 127, q = a >> 5, s2 = a & 31;
    atomicAdd(&proto_g[cls * D + s2 * 4 + q], p_loc[i]);
  }
}

__global__ void k_final(const float* __restrict__ proto_g,
                        const float* __restrict__ cnt_g,
                        float* __restrict__ out) {
  int i = blockIdx.x * BLOCK + threadIdx.x;
  if (i < C * D) out[i] = proto_g[i] / fmaxf(cnt_g[i / D], 1.f);
}

}  // namespace

extern "C" void kernel_launch(void* const* d_in, const int* in_sizes, int n_in,
                              void* d_out, int out_size, void* d_ws, size_t ws_size,
                              hipStream_t stream) {
  const float* feat = (const float*)d_in[0];
  const int* lab = (const int*)d_in[1];
  const int n = in_sizes[0] / D;

  // ws layout: m[C*D] | cnt[C] | proto[C*D]   (all fp32, zeroed)
  float* m_g = (float*)d_ws;
  float* cnt_g = m_g + C * D;
  float* proto_g = cnt_g + C;
  hipMemsetAsync(d_ws, 0, (size_t)(2 * C * D + C) * sizeof(float), stream);

  k_stats<<<GRID, BLOCK, 0, stream>>>((const float4*)feat, lab, m_g, cnt_g, n);
  k_proto<<<GRID, BLOCK, 0, stream>>>((const float4*)feat, lab, (const float4*)m_g,
                                      cnt_g, proto_g, n);
  k_final<<<(C * D + BLOCK - 1) / BLOCK, BLOCK, 0, stream>>>(proto_g, cnt_g, (float*)d_out);
}